// Round 1
// 274.888 us; speedup vs baseline: 1.0615x; 1.0615x over previous
//
#include <hip/hip_runtime.h>

#define N_NODES 50000
#define N_EDGES 800000
#define NEG_SLOPE 0.2f
#define BN_EPS  1e-5f
#define LOG2E   1.44269504088896f

#define CHUNKS 256            // edge chunks for counting sort
#define EDGES_PER_CHUNK 3125  // 256*3125 = 800000 exactly
#define NCOARSE 1024          // coarse buckets = dst>>6
#define NBUCKET 782           // ceil(50000/64) live buckets

typedef short bf16x8 __attribute__((ext_vector_type(8)));
typedef float floatx4 __attribute__((ext_vector_type(4)));

__device__ inline ushort f2bf(float f) {
    union { float f; unsigned u; } v; v.f = f;
    unsigned r = v.u + 0x7fff + ((v.u >> 16) & 1);
    return (ushort)(r >> 16);
}
__device__ inline float bf2f(ushort h) {
    union { unsigned u; float f; } v; v.u = ((unsigned)h) << 16;
    return v.f;
}

// ---------------------------------------------------------------------------
// Pass A + W-transpose fused:
//   blocks [0,256)   : LDS histogram of coarse bucket (dst>>6) over this
//                      block's 3125-edge chunk -> counts[bucket*CHUNKS+chunk]
//   blocks [256,512) : W fp32 [K][N] -> Wt bf16 [N][K]; block 256 also zeros
//                      the BN accumulators (was in sscan2).
// ---------------------------------------------------------------------------
__global__ __launch_bounds__(256) void count_wt_kernel(const int* __restrict__ ei,
                                                       const float* __restrict__ W,
                                                       int* __restrict__ counts,
                                                       ushort* __restrict__ Wtb,
                                                       float* __restrict__ gsum,
                                                       float* __restrict__ gsumsq)
{
    __shared__ int hist[NCOARSE];
    const int t = threadIdx.x;
    const int b = blockIdx.x;
    if (b < CHUNKS) {
        for (int j = t; j < NCOARSE; j += 256) hist[j] = 0;
        __syncthreads();
        const int e0 = b * EDGES_PER_CHUNK;
        for (int e = e0 + t; e < e0 + EDGES_PER_CHUNK; e += 256)
            atomicAdd(&hist[ei[N_EDGES + e] >> 6], 1);
        __syncthreads();
        for (int j = t; j < NCOARSE; j += 256)
            counts[j * CHUNKS + b] = hist[j];   // bucket-major for the scan
    } else {
        const int n = b - CHUNKS;               // output col
        Wtb[n * 256 + t] = f2bf(W[t * 256 + n]);
        if (n == 0) { gsum[t] = 0.f; gsumsq[t] = 0.f; }
    }
}

// ---------------------------------------------------------------------------
// sscan1 (1024 blocks): block g = bucket g; exclusive scan of its 256
// per-chunk counts in place; blocksum[g] = bucket total.
// ---------------------------------------------------------------------------
__global__ __launch_bounds__(256) void sscan1_kernel(int* __restrict__ counts,
                                                     int* __restrict__ blocksum)
{
    __shared__ int sm[256];
    const int t = threadIdx.x;
    const int i = blockIdx.x * 256 + t;
    const int v = counts[i];
    sm[t] = v;
    __syncthreads();
#pragma unroll
    for (int off = 1; off < 256; off <<= 1) {
        const int u = (t >= off) ? sm[t - off] : 0;
        __syncthreads();
        sm[t] += u;
        __syncthreads();
    }
    counts[i] = sm[t] - v;  // bucket-local exclusive
    if (t == 255) blocksum[blockIdx.x] = sm[255];
}

// ---------------------------------------------------------------------------
// Pass B (sscan2 folded in): every block redundantly scans blocksum[1024]
// in LDS (~2 us, fully parallel -> removes the serial 1-block sscan2 launch).
// Block 0 also publishes blockbase to global for bucket_build.
// Then bucket-partitioned scatter as before: LDS cursors, tmp packed
// (src<<6)|(dst&63). LDS atomics only.
// ---------------------------------------------------------------------------
__global__ __launch_bounds__(256) void bucket_scatter_kernel(const int* __restrict__ ei,
                                                             const int* __restrict__ counts,
                                                             const int* __restrict__ blocksum,
                                                             int* __restrict__ blockbase,
                                                             uint* __restrict__ tmp)
{
    __shared__ int sm[256];
    __shared__ int bbase[NCOARSE];
    __shared__ int cursor[NCOARSE];
    const int t = threadIdx.x;
    const int blk = blockIdx.x;

    int v[4], loc[4], tot = 0;
#pragma unroll
    for (int j = 0; j < 4; ++j) {
        v[j] = blocksum[t * 4 + j];
        loc[j] = tot;
        tot += v[j];
    }
    sm[t] = tot;
    __syncthreads();
#pragma unroll
    for (int off = 1; off < 256; off <<= 1) {
        const int u = (t >= off) ? sm[t - off] : 0;
        __syncthreads();
        sm[t] += u;
        __syncthreads();
    }
    const int base = sm[t] - tot;
#pragma unroll
    for (int j = 0; j < 4; ++j) bbase[t * 4 + j] = base + loc[j];
    if (blk == 0) {
#pragma unroll
        for (int j = 0; j < 4; ++j) blockbase[t * 4 + j] = base + loc[j];
    }
    __syncthreads();

    for (int u = t; u < NCOARSE; u += 256)
        cursor[u] = counts[u * CHUNKS + blk] + bbase[u];
    __syncthreads();
    const int e0 = blk * EDGES_PER_CHUNK;
    for (int e = e0 + t; e < e0 + EDGES_PER_CHUNK; e += 256) {
        const int src = ei[e];
        const int dst = ei[N_EDGES + e];
        const int pos = atomicAdd(&cursor[dst >> 6], 1);
        tmp[pos] = ((uint)src << 6) | (uint)(dst & 63);
    }
}

// ---------------------------------------------------------------------------
// Pass C: per-bucket CSR build (782 blocks, ~1020 edges each):
// LDS 64-bin hist over dst&63 -> LDS scan -> offsets[]; LDS-cursor scatter
// of src into csr_src. LDS atomics only.
// ---------------------------------------------------------------------------
__global__ __launch_bounds__(256) void bucket_build_kernel(const uint* __restrict__ tmp,
                                                           const int* __restrict__ blockbase,
                                                           int* __restrict__ offsets,
                                                           int* __restrict__ csr_src)
{
    __shared__ int hist[64];
    __shared__ int sbuf[64];
    __shared__ int cursor[64];
    const int t = threadIdx.x;
    const int b = blockIdx.x;            // bucket: nodes [b*64, b*64+64)
    const int start = blockbase[b];
    const int end   = blockbase[b + 1];  // buckets >= NBUCKET are empty (==E)
    if (t < 64) hist[t] = 0;
    __syncthreads();
    for (int e = start + t; e < end; e += 256)
        atomicAdd(&hist[tmp[e] & 63], 1);
    __syncthreads();
    const int v = (t < 64) ? hist[t] : 0;
    if (t < 64) sbuf[t] = v;
    __syncthreads();
#pragma unroll
    for (int off = 1; off < 64; off <<= 1) {
        int u = 0;
        if (t < 64 && t >= off) u = sbuf[t - off];
        __syncthreads();
        if (t < 64) sbuf[t] += u;
        __syncthreads();
    }
    if (t < 64) {
        const int excl = start + sbuf[t] - v;
        cursor[t] = excl;
        const int node = b * 64 + t;
        if (node < N_NODES) offsets[node] = excl;
    }
    if (b == 0 && t == 0) offsets[N_NODES] = N_EDGES;
    __syncthreads();
    for (int e = start + t; e < end; e += 256) {
        const uint p = tmp[e];
        const int pos = atomicAdd(&cursor[p & 63], 1);
        csr_src[pos] = (int)(p >> 6);
    }
}

// ---------------------------------------------------------------------------
// MFMA GEMM, BM=64 x BN=256 (A fp32 read ONCE instead of twice):
// 782 blocks of 256 threads; wave w owns head w (64-col block), rows 0..63.
// B-tile (full Wt, 128 KB) is L2-resident across all blocks.
// Epilogue: permuted xb stores + per-node attention logits s,d pre-scaled
// by log2(e) (exact: leaky-relu is positively homogeneous) so aggregate
// can use exp2 directly.
// ---------------------------------------------------------------------------
#define LDSTRIDE 40  // 32 + 8 pad: 2-way max bank aliasing (free)
__global__ __launch_bounds__(256) void gemm_kernel(const float* __restrict__ A,
                                                   const ushort* __restrict__ Bt,
                                                   const float* __restrict__ att_src,
                                                   const float* __restrict__ att_dst,
                                                   ushort* __restrict__ Xb,
                                                   float* __restrict__ s,
                                                   float* __restrict__ d)
{
    __shared__ ushort As[64 * LDSTRIDE];
    __shared__ ushort Bs[256 * LDSTRIDE];
    const int tid = threadIdx.x;
    const int lane = tid & 63;
    const int wid = tid >> 6;            // wave = head (64-col block)
    const int row0 = blockIdx.x * 64;
    const int quad = lane >> 4;
    const int l16  = lane & 15;

    floatx4 acc[4][4] = {};  // [mi][ni]

    const int lr = tid >> 2;        // 0..63 (row)
    const int lk = (tid & 3) * 8;   // 0,8,16,24 (k elem offset)

    for (int k0 = 0; k0 < 256; k0 += 32) {
        {   // A: 64 rows x 32 k, fp32 -> bf16 in staging
            const int grow = row0 + lr;
            union { ushort u[8]; ulonglong2 v; } cv;
            if (grow < N_NODES) {
                const float4 f0 = *(const float4*)(A + (size_t)grow * 256 + k0 + lk);
                const float4 f1 = *(const float4*)(A + (size_t)grow * 256 + k0 + lk + 4);
                cv.u[0] = f2bf(f0.x); cv.u[1] = f2bf(f0.y);
                cv.u[2] = f2bf(f0.z); cv.u[3] = f2bf(f0.w);
                cv.u[4] = f2bf(f1.x); cv.u[5] = f2bf(f1.y);
                cv.u[6] = f2bf(f1.z); cv.u[7] = f2bf(f1.w);
            } else {
                cv.v = ulonglong2{0ull, 0ull};
            }
            *(ulonglong2*)(As + lr * LDSTRIDE + lk) = cv.v;
        }
#pragma unroll
        for (int r = 0; r < 4; ++r) {   // B: 256 rows x 32 k (L2-hot)
            const int row = lr + r * 64;
            const ulonglong2 bv = *(const ulonglong2*)(Bt + (size_t)row * 256 + k0 + lk);
            *(ulonglong2*)(Bs + row * LDSTRIDE + lk) = bv;
        }
        __syncthreads();
        bf16x8 afrag[4], bfrag[4];
#pragma unroll
        for (int mi = 0; mi < 4; ++mi)
            afrag[mi] = *(const bf16x8*)(As + (mi * 16 + l16) * LDSTRIDE + quad * 8);
#pragma unroll
        for (int ni = 0; ni < 4; ++ni)
            bfrag[ni] = *(const bf16x8*)(Bs + (wid * 64 + ni * 16 + l16) * LDSTRIDE + quad * 8);
#pragma unroll
        for (int mi = 0; mi < 4; ++mi)
#pragma unroll
            for (int ni = 0; ni < 4; ++ni)
                acc[mi][ni] = __builtin_amdgcn_mfma_f32_16x16x32_bf16(afrag[mi], bfrag[ni], acc[mi][ni], 0, 0, 0);
        __syncthreads();
    }

    const int head = wid;
    float as_l[4], ad_l[4];
#pragma unroll
    for (int ni = 0; ni < 4; ++ni) {
        const int ch = head * 64 + ni * 16 + l16;  // true channel
        as_l[ni] = att_src[ch];
        ad_l[ni] = att_dst[ch];
    }
#pragma unroll
    for (int mi = 0; mi < 4; ++mi) {
#pragma unroll
        for (int r = 0; r < 4; ++r) {
            const int grow = row0 + mi * 16 + quad * 4 + r;
            const bool ok = grow < N_NODES;
            float vs = 0.f, vd = 0.f;
            ushort4 o;
#pragma unroll
            for (int ni = 0; ni < 4; ++ni) {
                const float v = acc[mi][ni][r];
                vs += v * as_l[ni];
                vd += v * ad_l[ni];
                ((ushort*)&o)[ni] = f2bf(v);
            }
            if (ok)  // permuted: pos within head block = l16*4 + ni
                *(ushort4*)(Xb + (size_t)grow * 256 + head * 64 + l16 * 4) = o;
#pragma unroll
            for (int m = 8; m >= 1; m >>= 1) {
                vs += __shfl_xor(vs, m);
                vd += __shfl_xor(vd, m);
            }
            if (l16 == 0 && ok) {
                s[grow * 4 + head] = vs * LOG2E;   // pre-scaled for exp2
                d[grow * 4 + head] = vd * LOG2E;
            }
        }
    }
}

// ---------------------------------------------------------------------------
// Aggregate: softmax-weighted gather per dst node (self-loop included).
// One wave per node; lane l owns permuted positions [4l,4l+4); head = l>>4.
// Edge indices made wave-uniform via readfirstlane -> csr loads go scalar
// (s_load), gather bases live in SGPRs (saddr-form loads, SALU addr math).
// Logits are pre-scaled by log2(e) -> exp2f directly.
// ---------------------------------------------------------------------------
__global__ __launch_bounds__(256) void aggregate_kernel(const ushort* __restrict__ xb,
                                                        const float* __restrict__ s,
                                                        const float* __restrict__ d,
                                                        const int* __restrict__ offsets,
                                                        const int* __restrict__ csr_src,
                                                        ushort* __restrict__ hagg)
{
    const int wid = threadIdx.x >> 6;
    const int lane = threadIdx.x & 63;
    const int n = blockIdx.x * 4 + wid;
    if (n >= N_NODES) return;
    const int h = lane >> 4;
    const float dn = d[n * 4 + h];
    const float sn = s[n * 4 + h];
    const ushort4 xr = *(const ushort4*)(xb + (size_t)n * 256 + lane * 4);
    float eself = sn + dn;
    eself = eself >= 0.f ? eself : NEG_SLOPE * eself;
    const float pself = exp2f(eself);
    float den = pself;
    float a0 = pself * bf2f(xr.x), a1 = pself * bf2f(xr.y);
    float a2 = pself * bf2f(xr.z), a3 = pself * bf2f(xr.w);
    const int e0 = __builtin_amdgcn_readfirstlane(offsets[n]);
    const int e1 = __builtin_amdgcn_readfirstlane(offsets[n + 1]);
    int e = e0;
    for (; e + 8 <= e1; e += 8) {
        int si[8];
        float lg[8];
        ushort4 xv[8];
#pragma unroll
        for (int j = 0; j < 8; ++j) si[j] = __builtin_amdgcn_readfirstlane(csr_src[e + j]);
#pragma unroll
        for (int j = 0; j < 8; ++j) lg[j] = s[si[j] * 4 + h] + dn;
#pragma unroll
        for (int j = 0; j < 8; ++j)
            xv[j] = *(const ushort4*)(xb + (size_t)si[j] * 256 + lane * 4);
#pragma unroll
        for (int j = 0; j < 8; ++j) {
            float l = lg[j];
            l = l >= 0.f ? l : NEG_SLOPE * l;
            const float p = exp2f(l);
            den += p;
            a0 += p * bf2f(xv[j].x);
            a1 += p * bf2f(xv[j].y);
            a2 += p * bf2f(xv[j].z);
            a3 += p * bf2f(xv[j].w);
        }
    }
    for (; e < e1; ++e) {
        const int src = __builtin_amdgcn_readfirstlane(csr_src[e]);
        float ee = s[src * 4 + h] + dn;
        ee = ee >= 0.f ? ee : NEG_SLOPE * ee;
        const float pe = exp2f(ee);
        const ushort4 xs = *(const ushort4*)(xb + (size_t)src * 256 + lane * 4);
        a0 += pe * bf2f(xs.x); a1 += pe * bf2f(xs.y);
        a2 += pe * bf2f(xs.z); a3 += pe * bf2f(xs.w);
        den += pe;
    }
    const float inv = 1.0f / den;
    ushort4 o;
    o.x = f2bf(a0 * inv); o.y = f2bf(a1 * inv);
    o.z = f2bf(a2 * inv); o.w = f2bf(a3 * inv);
    *(ushort4*)(hagg + (size_t)n * 256 + lane * 4) = o;
}

// ---------------------------------------------------------------------------
// BatchNorm stats over bf16 h (permuted channels; bias cancels, ignored).
// ---------------------------------------------------------------------------
#define BN_BLOCKS 784  // 784*64 = 50176 >= 50000
__global__ __launch_bounds__(256) void bn_stats_kernel(const ushort* __restrict__ hagg,
                                                       float* __restrict__ gsum,
                                                       float* __restrict__ gsumsq)
{
    const int c = threadIdx.x;  // permuted channel
    const int r0 = blockIdx.x * 64;
    float sum = 0.f, sq = 0.f;
#pragma unroll 4
    for (int i = 0; i < 64; ++i) {
        const int r = r0 + i;
        if (r < N_NODES) {
            const float v = bf2f(hagg[(size_t)r * 256 + c]);
            sum += v;
            sq += v * v;
        }
    }
    atomicAdd(&gsum[c], sum);
    atomicAdd(&gsumsq[c], sq);
}

// ---------------------------------------------------------------------------
// Finalize: un-permute hagg through LDS so feature loads / out stores are
// float4-coalesced. 3125 blocks x 16 nodes. BN params computed per true
// channel (gsum/gsumsq are indexed by PERMUTED channel -> inverse map).
// ---------------------------------------------------------------------------
__global__ __launch_bounds__(256) void finalize_kernel(const float* __restrict__ feature,
                                                       const ushort* __restrict__ hagg,
                                                       const float* __restrict__ gsum,
                                                       const float* __restrict__ gsumsq,
                                                       const float* __restrict__ gamma,
                                                       const float* __restrict__ beta,
                                                       float* __restrict__ out)
{
    __shared__ ushort hs[16][264];   // 16 rows, unpermuted, +8 pad
    const int t = threadIdx.x;
    const int wid = t >> 6;
    const int lane = t & 63;
    const int row0 = blockIdx.x * 16;
    const int hblk = lane >> 4;
    const int l16 = lane & 15;

    // phase 1: coalesced hagg loads, permuted->true scatter into LDS.
    // permuted pos p = lane*4+j holds true channel hblk*64 + j*16 + l16.
#pragma unroll
    for (int rr = 0; rr < 4; ++rr) {
        const int r = wid * 4 + rr;
        const int n = row0 + r;
        const ushort4 hv = *(const ushort4*)(hagg + (size_t)n * 256 + lane * 4);
        hs[r][hblk * 64 + 0 * 16 + l16] = hv.x;
        hs[r][hblk * 64 + 1 * 16 + l16] = hv.y;
        hs[r][hblk * 64 + 2 * 16 + l16] = hv.z;
        hs[r][hblk * 64 + 3 * 16 + l16] = hv.w;
    }

    // phase 2 params: true channel tc = lane*4+j; its permuted slot:
    // w = tc&63, p = (tc>>6)*64 + (w&15)*4 + (w>>4)
    float meanv[4], scalev[4], betav[4];
#pragma unroll
    for (int j = 0; j < 4; ++j) {
        const int tc = lane * 4 + j;
        const int w = tc & 63;
        const int p = (tc >> 6) * 64 + ((w & 15) << 2) + (w >> 4);
        const float m = gsum[p] * (1.0f / N_NODES);
        const float var = gsumsq[p] * (1.0f / N_NODES) - m * m;
        meanv[j] = m;
        scalev[j] = gamma[tc] * rsqrtf(var + BN_EPS);
        betav[j] = beta[tc];
    }
    __syncthreads();

    // phase 3: float4-coalesced normalize + ELU + residual
#pragma unroll
    for (int rr = 0; rr < 4; ++rr) {
        const int r = wid * 4 + rr;
        const int n = row0 + r;
        const ushort4 hv = *(const ushort4*)(&hs[r][lane * 4]);
        const float4 fv = *(const float4*)(feature + (size_t)n * 256 + lane * 4);
        const float hvf[4] = {bf2f(hv.x), bf2f(hv.y), bf2f(hv.z), bf2f(hv.w)};
        float4 o;
        float* op = (float*)&o;
        const float* fp = (const float*)&fv;
#pragma unroll
        for (int j = 0; j < 4; ++j) {
            float v = (hvf[j] - meanv[j]) * scalev[j] + betav[j];
            v = v > 0.f ? v : expm1f(v);
            op[j] = v + fp[j];
        }
        *(float4*)(out + (size_t)n * 256 + lane * 4) = o;
    }
}

// ---------------------------------------------------------------------------
extern "C" void kernel_launch(void* const* d_in, const int* in_sizes, int n_in,
                              void* d_out, int out_size, void* d_ws, size_t ws_size,
                              hipStream_t stream)
{
    const float* feature = (const float*)d_in[0];
    const int*   ei      = (const int*)d_in[1];
    const float* W       = (const float*)d_in[2];
    const float* att_src = (const float*)d_in[3];
    const float* att_dst = (const float*)d_in[4];
    // d_in[5] = bias: cancels inside batchnorm, unused
    const float* gamma   = (const float*)d_in[6];
    const float* beta    = (const float*)d_in[7];
    float* out = (float*)d_out;

    char* w = (char*)d_ws;
    auto carve = [&](size_t bytes) {
        char* p = w;
        w += (bytes + 255) & ~(size_t)255;
        return p;
    };
    ushort* Wtb      = (ushort*)carve((size_t)256 * 256 * 2);
    ushort* xb       = (ushort*)carve((size_t)N_NODES * 256 * 2);
    ushort* hagg     = (ushort*)carve((size_t)N_NODES * 256 * 2);
    float*  s        = (float*)carve((size_t)N_NODES * 4 * 4);
    float*  dv       = (float*)carve((size_t)N_NODES * 4 * 4);
    int*    counts   = (int*)carve((size_t)NCOARSE * CHUNKS * 4);  // 1 MB
    int*    offsets  = (int*)carve((size_t)(N_NODES + 1) * 4);
    int*    csr_src  = (int*)carve((size_t)N_EDGES * 4);
    int*    blocksum = (int*)carve((size_t)NCOARSE * 4);
    int*    blockbase= (int*)carve((size_t)NCOARSE * 4);
    float*  gsum     = (float*)carve(256 * 4);
    float*  gsumsq   = (float*)carve(256 * 4);
    // tmp (3.2 MB packed edges) aliases hagg: dead until aggregate writes it;
    // bucket_build (last tmp reader) runs before aggregate.
    uint*   tmp      = (uint*)hagg;

    count_wt_kernel<<<512, 256, 0, stream>>>(ei, W, counts, Wtb, gsum, gsumsq);
    sscan1_kernel<<<NCOARSE, 256, 0, stream>>>(counts, blocksum);
    bucket_scatter_kernel<<<CHUNKS, 256, 0, stream>>>(ei, counts, blocksum, blockbase, tmp);
    bucket_build_kernel<<<NBUCKET, 256, 0, stream>>>(tmp, blockbase, offsets, csr_src);
    gemm_kernel<<<782, 256, 0, stream>>>(feature, Wtb, att_src, att_dst, xb, s, dv);
    aggregate_kernel<<<12500, 256, 0, stream>>>(xb, s, dv, offsets, csr_src, hagg);
    bn_stats_kernel<<<BN_BLOCKS, 256, 0, stream>>>(hagg, gsum, gsumsq);
    finalize_kernel<<<3125, 256, 0, stream>>>(feature, hagg, gsum, gsumsq, gamma, beta, out);
}

// Round 2
// 243.384 us; speedup vs baseline: 1.1989x; 1.1294x over previous
//
#include <hip/hip_runtime.h>

#define N_NODES 50000
#define N_EDGES 800000
#define NEG_SLOPE 0.2f
#define BN_EPS  1e-5f
#define LOG2E   1.44269504088896f

#define CHUNKS 256            // edge chunks for counting sort
#define EDGES_PER_CHUNK 3125  // 256*3125 = 800000 exactly
#define NCOARSE 1024          // coarse buckets = dst>>6
#define NBUCKET 782           // ceil(50000/64) live buckets
#define GEMM_BLOCKS 782       // ceil(50000/64) row tiles

typedef short bf16x8 __attribute__((ext_vector_type(8)));
typedef float floatx4 __attribute__((ext_vector_type(4)));

__device__ inline ushort f2bf(float f) {
    union { float f; unsigned u; } v; v.f = f;
    unsigned r = v.u + 0x7fff + ((v.u >> 16) & 1);
    return (ushort)(r >> 16);
}
__device__ inline float bf2f(ushort h) {
    union { unsigned u; float f; } v; v.u = ((unsigned)h) << 16;
    return v.f;
}

// ---------------------------------------------------------------------------
// Pass A + W-transpose fused:
//   blocks [0,256)   : LDS histogram of coarse bucket (dst>>6) over this
//                      block's 3125-edge chunk -> counts[bucket*CHUNKS+chunk]
//   blocks [256,512) : W fp32 [K][N] -> Wt bf16 [N][K]; blocks 256..271 also
//                      zero the 8-replica BN accumulators (8*256*2 floats).
// ---------------------------------------------------------------------------
__global__ __launch_bounds__(256) void count_wt_kernel(const int* __restrict__ ei,
                                                       const float* __restrict__ W,
                                                       int* __restrict__ counts,
                                                       ushort* __restrict__ Wtb,
                                                       float* __restrict__ bnacc)
{
    __shared__ int hist[NCOARSE];
    const int t = threadIdx.x;
    const int b = blockIdx.x;
    if (b < CHUNKS) {
        for (int j = t; j < NCOARSE; j += 256) hist[j] = 0;
        __syncthreads();
        const int e0 = b * EDGES_PER_CHUNK;
        for (int e = e0 + t; e < e0 + EDGES_PER_CHUNK; e += 256)
            atomicAdd(&hist[ei[N_EDGES + e] >> 6], 1);
        __syncthreads();
        for (int j = t; j < NCOARSE; j += 256)
            counts[j * CHUNKS + b] = hist[j];   // bucket-major for the scan
    } else {
        const int n = b - CHUNKS;               // output col
        Wtb[n * 256 + t] = f2bf(W[t * 256 + n]);
        if (n < 16) bnacc[n * 256 + t] = 0.f;   // 16*256 = 4096 floats
    }
}

// ---------------------------------------------------------------------------
// sscan1 (1024 blocks): block g = bucket g; exclusive scan of its 256
// per-chunk counts in place; blocksum[g] = bucket total.
// ---------------------------------------------------------------------------
__global__ __launch_bounds__(256) void sscan1_kernel(int* __restrict__ counts,
                                                     int* __restrict__ blocksum)
{
    __shared__ int sm[256];
    const int t = threadIdx.x;
    const int i = blockIdx.x * 256 + t;
    const int v = counts[i];
    sm[t] = v;
    __syncthreads();
#pragma unroll
    for (int off = 1; off < 256; off <<= 1) {
        const int u = (t >= off) ? sm[t - off] : 0;
        __syncthreads();
        sm[t] += u;
        __syncthreads();
    }
    counts[i] = sm[t] - v;  // bucket-local exclusive
    if (t == 255) blocksum[blockIdx.x] = sm[255];
}

// ---------------------------------------------------------------------------
// FUSED scatter + GEMM (1038 blocks): scatter is independent of GEMM, so the
// 256 scatter blocks hide entirely under the 782 GEMM blocks in one dispatch.
// Shared memory is a 25.6 KB union (scatter: 9.2 KB of cursors; gemm: As+Bs).
//
// blocks [0,256): sscan2 folded in (every block redundantly scans
// blocksum[1024] in LDS; block 0 publishes blockbase) + bucket-partitioned
// scatter: tmp packed (src<<6)|(dst&63), LDS atomics only.
//
// blocks [256,1038): MFMA GEMM, BM=64 x BN=256 (A fp32 read once). Wave w
// owns head w. Epilogue: permuted xb stores + attention logits s,d
// pre-scaled by log2(e) (exact: leaky-relu is positively homogeneous).
// ---------------------------------------------------------------------------
#define LDSTRIDE 40  // 32 + 8 pad: 2-way max bank aliasing (free)
__global__ __launch_bounds__(256) void scatter_gemm_kernel(const int* __restrict__ ei,
                                                           const int* __restrict__ counts,
                                                           const int* __restrict__ blocksum,
                                                           int* __restrict__ blockbase,
                                                           uint* __restrict__ tmp,
                                                           const float* __restrict__ A,
                                                           const ushort* __restrict__ Bt,
                                                           const float* __restrict__ att_src,
                                                           const float* __restrict__ att_dst,
                                                           ushort* __restrict__ Xb,
                                                           float* __restrict__ s,
                                                           float* __restrict__ d)
{
    __shared__ __align__(16) char smem[25600];
    const int tid = threadIdx.x;

    if (blockIdx.x < CHUNKS) {
        // ---------------- scatter branch ----------------
        int* sm     = (int*)smem;          // [256]
        int* bbase  = sm + 256;            // [1024]
        int* cursor = bbase + NCOARSE;     // [1024]
        const int t = tid;
        const int blk = blockIdx.x;

        int v[4], loc[4], tot = 0;
#pragma unroll
        for (int j = 0; j < 4; ++j) {
            v[j] = blocksum[t * 4 + j];
            loc[j] = tot;
            tot += v[j];
        }
        sm[t] = tot;
        __syncthreads();
#pragma unroll
        for (int off = 1; off < 256; off <<= 1) {
            const int u = (t >= off) ? sm[t - off] : 0;
            __syncthreads();
            sm[t] += u;
            __syncthreads();
        }
        const int base = sm[t] - tot;
#pragma unroll
        for (int j = 0; j < 4; ++j) bbase[t * 4 + j] = base + loc[j];
        if (blk == 0) {
#pragma unroll
            for (int j = 0; j < 4; ++j) blockbase[t * 4 + j] = base + loc[j];
        }
        __syncthreads();

        for (int u = t; u < NCOARSE; u += 256)
            cursor[u] = counts[u * CHUNKS + blk] + bbase[u];
        __syncthreads();
        const int e0 = blk * EDGES_PER_CHUNK;
        for (int e = e0 + t; e < e0 + EDGES_PER_CHUNK; e += 256) {
            const int src = ei[e];
            const int dst = ei[N_EDGES + e];
            const int pos = atomicAdd(&cursor[dst >> 6], 1);
            tmp[pos] = ((uint)src << 6) | (uint)(dst & 63);
        }
        return;
    }

    // ---------------- gemm branch ----------------
    ushort* As = (ushort*)smem;        // [64 * LDSTRIDE]  = 5120 B
    ushort* Bs = As + 64 * LDSTRIDE;   // [256 * LDSTRIDE] = 20480 B
    const int lane = tid & 63;
    const int wid = tid >> 6;            // wave = head (64-col block)
    const int row0 = (blockIdx.x - CHUNKS) * 64;
    const int quad = lane >> 4;
    const int l16  = lane & 15;

    floatx4 acc[4][4] = {};  // [mi][ni]

    const int lr = tid >> 2;        // 0..63 (row)
    const int lk = (tid & 3) * 8;   // 0,8,16,24 (k elem offset)

    for (int k0 = 0; k0 < 256; k0 += 32) {
        {   // A: 64 rows x 32 k, fp32 -> bf16 in staging
            const int grow = row0 + lr;
            union { ushort u[8]; ulonglong2 v; } cv;
            if (grow < N_NODES) {
                const float4 f0 = *(const float4*)(A + (size_t)grow * 256 + k0 + lk);
                const float4 f1 = *(const float4*)(A + (size_t)grow * 256 + k0 + lk + 4);
                cv.u[0] = f2bf(f0.x); cv.u[1] = f2bf(f0.y);
                cv.u[2] = f2bf(f0.z); cv.u[3] = f2bf(f0.w);
                cv.u[4] = f2bf(f1.x); cv.u[5] = f2bf(f1.y);
                cv.u[6] = f2bf(f1.z); cv.u[7] = f2bf(f1.w);
            } else {
                cv.v = ulonglong2{0ull, 0ull};
            }
            *(ulonglong2*)(As + lr * LDSTRIDE + lk) = cv.v;
        }
#pragma unroll
        for (int r = 0; r < 4; ++r) {   // B: 256 rows x 32 k (L2-hot)
            const int row = lr + r * 64;
            const ulonglong2 bv = *(const ulonglong2*)(Bt + (size_t)row * 256 + k0 + lk);
            *(ulonglong2*)(Bs + row * LDSTRIDE + lk) = bv;
        }
        __syncthreads();
        bf16x8 afrag[4], bfrag[4];
#pragma unroll
        for (int mi = 0; mi < 4; ++mi)
            afrag[mi] = *(const bf16x8*)(As + (mi * 16 + l16) * LDSTRIDE + quad * 8);
#pragma unroll
        for (int ni = 0; ni < 4; ++ni)
            bfrag[ni] = *(const bf16x8*)(Bs + (wid * 64 + ni * 16 + l16) * LDSTRIDE + quad * 8);
#pragma unroll
        for (int mi = 0; mi < 4; ++mi)
#pragma unroll
            for (int ni = 0; ni < 4; ++ni)
                acc[mi][ni] = __builtin_amdgcn_mfma_f32_16x16x32_bf16(afrag[mi], bfrag[ni], acc[mi][ni], 0, 0, 0);
        __syncthreads();
    }

    const int head = wid;
    float as_l[4], ad_l[4];
#pragma unroll
    for (int ni = 0; ni < 4; ++ni) {
        const int ch = head * 64 + ni * 16 + l16;  // true channel
        as_l[ni] = att_src[ch];
        ad_l[ni] = att_dst[ch];
    }
#pragma unroll
    for (int mi = 0; mi < 4; ++mi) {
#pragma unroll
        for (int r = 0; r < 4; ++r) {
            const int grow = row0 + mi * 16 + quad * 4 + r;
            const bool ok = grow < N_NODES;
            float vs = 0.f, vd = 0.f;
            ushort4 o;
#pragma unroll
            for (int ni = 0; ni < 4; ++ni) {
                const float v = acc[mi][ni][r];
                vs += v * as_l[ni];
                vd += v * ad_l[ni];
                ((ushort*)&o)[ni] = f2bf(v);
            }
            if (ok)  // permuted: pos within head block = l16*4 + ni
                *(ushort4*)(Xb + (size_t)grow * 256 + head * 64 + l16 * 4) = o;
#pragma unroll
            for (int m = 8; m >= 1; m >>= 1) {
                vs += __shfl_xor(vs, m);
                vd += __shfl_xor(vd, m);
            }
            if (l16 == 0 && ok) {
                s[grow * 4 + head] = vs * LOG2E;   // pre-scaled for exp2
                d[grow * 4 + head] = vd * LOG2E;
            }
        }
    }
}

// ---------------------------------------------------------------------------
// Pass C: per-bucket CSR build (782 blocks, ~1020 edges each):
// LDS 64-bin hist over dst&63 -> LDS scan -> offsets[]; LDS-cursor scatter
// of src into csr_src. LDS atomics only.
// ---------------------------------------------------------------------------
__global__ __launch_bounds__(256) void bucket_build_kernel(const uint* __restrict__ tmp,
                                                           const int* __restrict__ blockbase,
                                                           int* __restrict__ offsets,
                                                           int* __restrict__ csr_src)
{
    __shared__ int hist[64];
    __shared__ int sbuf[64];
    __shared__ int cursor[64];
    const int t = threadIdx.x;
    const int b = blockIdx.x;            // bucket: nodes [b*64, b*64+64)
    const int start = blockbase[b];
    const int end   = blockbase[b + 1];  // buckets >= NBUCKET are empty (==E)
    if (t < 64) hist[t] = 0;
    __syncthreads();
    for (int e = start + t; e < end; e += 256)
        atomicAdd(&hist[tmp[e] & 63], 1);
    __syncthreads();
    const int v = (t < 64) ? hist[t] : 0;
    if (t < 64) sbuf[t] = v;
    __syncthreads();
#pragma unroll
    for (int off = 1; off < 64; off <<= 1) {
        int u = 0;
        if (t < 64 && t >= off) u = sbuf[t - off];
        __syncthreads();
        if (t < 64) sbuf[t] += u;
        __syncthreads();
    }
    if (t < 64) {
        const int excl = start + sbuf[t] - v;
        cursor[t] = excl;
        const int node = b * 64 + t;
        if (node < N_NODES) offsets[node] = excl;
    }
    if (b == 0 && t == 0) offsets[N_NODES] = N_EDGES;
    __syncthreads();
    for (int e = start + t; e < end; e += 256) {
        const uint p = tmp[e];
        const int pos = atomicAdd(&cursor[p & 63], 1);
        csr_src[pos] = (int)(p >> 6);
    }
}

// ---------------------------------------------------------------------------
// Aggregate + BN stats fused: softmax-weighted gather per dst node.
// One wave per node (12500 blocks x 4 = 50000 exactly, no tail).
// Edge loop: fully predicated 8-groups (clamped index, invalid logit ->
// -1e30 -> p = 0 exactly) - no scalar cleanup tail. Dummy gathers hit L1.
// BN: block-level LDS reduce (per-wave private rows, float4 stores, no LDS
// atomics) -> 512 global atomicAdds into the XCD-local replica
// bnacc[blockIdx&7] (1562 adds/address - negligible contention).
// ---------------------------------------------------------------------------
__global__ __launch_bounds__(256) void aggregate_kernel(const ushort* __restrict__ xb,
                                                        const float* __restrict__ s,
                                                        const float* __restrict__ d,
                                                        const int* __restrict__ offsets,
                                                        const int* __restrict__ csr_src,
                                                        ushort* __restrict__ hagg,
                                                        float* __restrict__ bnacc)
{
    __shared__ float bsum[4][256];
    __shared__ float bsq[4][256];
    const int wid = threadIdx.x >> 6;
    const int lane = threadIdx.x & 63;
    const int n = blockIdx.x * 4 + wid;      // always < 50000
    const int h = lane >> 4;
    const float dn = d[n * 4 + h];
    const float sn = s[n * 4 + h];
    const ushort4 xr = *(const ushort4*)(xb + (size_t)n * 256 + lane * 4);
    float eself = sn + dn;
    eself = eself >= 0.f ? eself : NEG_SLOPE * eself;
    const float pself = exp2f(eself);
    float den = pself;
    float a0 = pself * bf2f(xr.x), a1 = pself * bf2f(xr.y);
    float a2 = pself * bf2f(xr.z), a3 = pself * bf2f(xr.w);
    const int e0 = __builtin_amdgcn_readfirstlane(offsets[n]);
    const int e1 = __builtin_amdgcn_readfirstlane(offsets[n + 1]);
    for (int e = e0; e < e1; e += 8) {
        int si[8];
        float lg[8];
        ushort4 xv[8];
#pragma unroll
        for (int j = 0; j < 8; ++j) {
            const int idx = e + j;
            const int idx2 = idx < e1 ? idx : e1 - 1;   // clamp (uniform)
            si[j] = __builtin_amdgcn_readfirstlane(csr_src[idx2]);
        }
#pragma unroll
        for (int j = 0; j < 8; ++j) lg[j] = s[si[j] * 4 + h] + dn;
#pragma unroll
        for (int j = 0; j < 8; ++j)
            xv[j] = *(const ushort4*)(xb + (size_t)si[j] * 256 + lane * 4);
#pragma unroll
        for (int j = 0; j < 8; ++j) {
            float l = (e + j < e1) ? lg[j] : -1e30f;    // dummy -> p = 0
            l = l >= 0.f ? l : NEG_SLOPE * l;
            const float p = exp2f(l);
            den += p;
            a0 += p * bf2f(xv[j].x);
            a1 += p * bf2f(xv[j].y);
            a2 += p * bf2f(xv[j].z);
            a3 += p * bf2f(xv[j].w);
        }
    }
    const float inv = 1.0f / den;
    ushort4 o;
    o.x = f2bf(a0 * inv); o.y = f2bf(a1 * inv);
    o.z = f2bf(a2 * inv); o.w = f2bf(a3 * inv);
    *(ushort4*)(hagg + (size_t)n * 256 + lane * 4) = o;

    // BN partials from the SAME rounded bf16 values finalize will read.
    const float v0 = bf2f(o.x), v1 = bf2f(o.y), v2 = bf2f(o.z), v3 = bf2f(o.w);
    *(float4*)&bsum[wid][lane * 4] = float4{v0, v1, v2, v3};
    *(float4*)&bsq[wid][lane * 4]  = float4{v0 * v0, v1 * v1, v2 * v2, v3 * v3};
    __syncthreads();
    const int c = threadIdx.x;               // permuted channel
    const float smv = bsum[0][c] + bsum[1][c] + bsum[2][c] + bsum[3][c];
    const float sqv = bsq[0][c]  + bsq[1][c]  + bsq[2][c]  + bsq[3][c];
    const int rep = (blockIdx.x & 7) * 256 + c;
    atomicAdd(&bnacc[rep], smv);
    atomicAdd(&bnacc[2048 + rep], sqv);
}

// ---------------------------------------------------------------------------
// Finalize: XCD-swizzled so each wave re-reads hagg rows written by aggregate
// blocks on the SAME XCD (b = 8k + xcd -> L2-private hit). BN mean/scale
// built once per block in LDS from the 8 replicas, indexed by true channel.
// Un-permute through LDS so feature/out are float4-coalesced.
// grid = 392*8 = 3136 blocks; wave handles aggregate block b (4 nodes).
// ---------------------------------------------------------------------------
__global__ __launch_bounds__(256) void finalize_kernel(const float* __restrict__ feature,
                                                       const ushort* __restrict__ hagg,
                                                       const float* __restrict__ bnacc,
                                                       const float* __restrict__ gamma,
                                                       const float* __restrict__ beta,
                                                       float* __restrict__ out)
{
    __shared__ ushort hs[16][264];   // 16 rows, unpermuted, +8 pad
    __shared__ float meanS[256], scaleS[256], betaS[256];
    const int t = threadIdx.x;
    const int wid = t >> 6;
    const int lane = t & 63;
    const int x = blockIdx.x & 7;            // target XCD
    const int i = blockIdx.x >> 3;           // 0..391
    const int bk = (i * 4 + wid) * 8 + x;    // aggregate block id
    const bool active = bk < 12500;
    const int hblk = lane >> 4;
    const int l16 = lane & 15;

    // phase 1: coalesced hagg loads (L2-hot), permuted->true scatter into LDS
    if (active) {
#pragma unroll
        for (int rr = 0; rr < 4; ++rr) {
            const int r = wid * 4 + rr;
            const int n = bk * 4 + rr;
            const ushort4 hv = *(const ushort4*)(hagg + (size_t)n * 256 + lane * 4);
            hs[r][hblk * 64 + 0 * 16 + l16] = hv.x;
            hs[r][hblk * 64 + 1 * 16 + l16] = hv.y;
            hs[r][hblk * 64 + 2 * 16 + l16] = hv.z;
            hs[r][hblk * 64 + 3 * 16 + l16] = hv.w;
        }
    }

    // BN tables: thread t owns permuted channel t; reduce the 8 replicas,
    // store mean/scale/beta at the TRUE channel index.
    {
        float smv = 0.f, sqv = 0.f;
#pragma unroll
        for (int r = 0; r < 8; ++r) {
            smv += bnacc[r * 256 + t];
            sqv += bnacc[2048 + r * 256 + t];
        }
        const float m = smv * (1.0f / N_NODES);
        const float var = sqv * (1.0f / N_NODES) - m * m;
        const int w = t & 63;
        const int tc = (t >> 6) * 64 + (w & 3) * 16 + (w >> 2);  // true channel
        meanS[tc] = m;
        scaleS[tc] = gamma[tc] * rsqrtf(var + BN_EPS);
        betaS[tc] = beta[tc];
    }
    __syncthreads();

    // phase 3: float4-coalesced normalize + ELU + residual
    if (active) {
#pragma unroll
        for (int rr = 0; rr < 4; ++rr) {
            const int r = wid * 4 + rr;
            const int n = bk * 4 + rr;
            const ushort4 hv = *(const ushort4*)(&hs[r][lane * 4]);
            const float4 fv = *(const float4*)(feature + (size_t)n * 256 + lane * 4);
            const float hvf[4] = {bf2f(hv.x), bf2f(hv.y), bf2f(hv.z), bf2f(hv.w)};
            float4 o;
            float* op = (float*)&o;
            const float* fp = (const float*)&fv;
#pragma unroll
            for (int j = 0; j < 4; ++j) {
                const int ch = lane * 4 + j;   // true channel
                float v = (hvf[j] - meanS[ch]) * scaleS[ch] + betaS[ch];
                v = v > 0.f ? v : expm1f(v);
                op[j] = v + fp[j];
            }
            *(float4*)(out + (size_t)n * 256 + lane * 4) = o;
        }
    }
}

// ---------------------------------------------------------------------------
extern "C" void kernel_launch(void* const* d_in, const int* in_sizes, int n_in,
                              void* d_out, int out_size, void* d_ws, size_t ws_size,
                              hipStream_t stream)
{
    const float* feature = (const float*)d_in[0];
    const int*   ei      = (const int*)d_in[1];
    const float* W       = (const float*)d_in[2];
    const float* att_src = (const float*)d_in[3];
    const float* att_dst = (const float*)d_in[4];
    // d_in[5] = bias: cancels inside batchnorm, unused
    const float* gamma   = (const float*)d_in[6];
    const float* beta    = (const float*)d_in[7];
    float* out = (float*)d_out;

    char* w = (char*)d_ws;
    auto carve = [&](size_t bytes) {
        char* p = w;
        w += (bytes + 255) & ~(size_t)255;
        return p;
    };
    ushort* Wtb      = (ushort*)carve((size_t)256 * 256 * 2);
    ushort* xb       = (ushort*)carve((size_t)N_NODES * 256 * 2);
    ushort* hagg     = (ushort*)carve((size_t)N_NODES * 256 * 2);
    float*  s        = (float*)carve((size_t)N_NODES * 4 * 4);
    float*  dv       = (float*)carve((size_t)N_NODES * 4 * 4);
    int*    counts   = (int*)carve((size_t)NCOARSE * CHUNKS * 4);  // 1 MB
    int*    offsets  = (int*)carve((size_t)(N_NODES + 1) * 4);
    int*    csr_src  = (int*)carve((size_t)N_EDGES * 4);
    int*    blocksum = (int*)carve((size_t)NCOARSE * 4);
    int*    blockbase= (int*)carve((size_t)NCOARSE * 4);
    float*  bnacc    = (float*)carve((size_t)4096 * 4);  // 8 replicas x 256 x {sum,sq}
    // tmp (3.2 MB packed edges) aliases hagg: dead until aggregate writes it;
    // bucket_build (last tmp reader) runs before aggregate.
    uint*   tmp      = (uint*)hagg;

    count_wt_kernel<<<512, 256, 0, stream>>>(ei, W, counts, Wtb, bnacc);
    sscan1_kernel<<<NCOARSE, 256, 0, stream>>>(counts, blocksum);
    scatter_gemm_kernel<<<CHUNKS + GEMM_BLOCKS, 256, 0, stream>>>(
        ei, counts, blocksum, blockbase, tmp,
        feature, Wtb, att_src, att_dst, xb, s, dv);
    bucket_build_kernel<<<NBUCKET, 256, 0, stream>>>(tmp, blockbase, offsets, csr_src);
    aggregate_kernel<<<12500, 256, 0, stream>>>(xb, s, dv, offsets, csr_src, hagg, bnacc);
    finalize_kernel<<<3136, 256, 0, stream>>>(feature, hagg, bnacc, gamma, beta, out);
}